// Round 3
// baseline (84.448 us; speedup 1.0000x reference)
//
#include <hip/hip_runtime.h>

// EMA / first-order low-pass scan: s_t = alpha[d] * s_{t-1} + x[b,d,t]
// x: [B, D, T] fp32 contiguous; alpha: [D] fp32.
// out: psp [B,D,T] followed by final_state [B,D] (flat, fp32).
//
// One 64-lane wave processes SPW=4 consecutive sequences (same b, d0..d0+3):
//  - 8 independent float4 loads issued up front (4x MLP vs 1-seq version)
//  - 4 independent wave-scans interleaved for ILP in the shfl chain
//  - nontemporal stores keep the output stream from evicting the input in L3

#define BB 32
#define DD 2048
#define TT 512
#define NSEQ (BB * DD)   // 65536 sequences
#define SPW 4            // sequences per wave

typedef float f32x4 __attribute__((ext_vector_type(4)));  // clang vector (nontemporal-store OK)

__global__ __launch_bounds__(256) void ema_scan4_kernel(
    const float* __restrict__ x,
    const float* __restrict__ alpha_arr,
    float* __restrict__ psp,
    float* __restrict__ final_state)
{
    const int gtid = blockIdx.x * 256 + threadIdx.x;
    const int wave = gtid >> 6;
    const int lane = threadIdx.x & 63;
    const int seq0 = wave * SPW;
    if (seq0 >= NSEQ) return;

    // 4 consecutive seqs share b; d = d0..d0+3 (d0 % 4 == 0) -> one float4 alpha load
    const int d0 = seq0 & (DD - 1);
    const f32x4 al4 = *reinterpret_cast<const f32x4*>(alpha_arr + d0);
    const float alpha[SPW] = {al4.x, al4.y, al4.z, al4.w};

    const float* xp = x + (size_t)seq0 * TT + (size_t)lane * 8;

    // Issue all 8 loads back-to-back (independent -> 128 B/lane in flight)
    f32x4 v[SPW][2];
    #pragma unroll
    for (int s = 0; s < SPW; ++s) {
        v[s][0] = *reinterpret_cast<const f32x4*>(xp + (size_t)s * TT);
        v[s][1] = *reinterpret_cast<const f32x4*>(xp + (size_t)s * TT + 4);
    }

    // Local inclusive scans (4 independent 8-FMA chains -> ILP)
    float y[SPW][8];
    #pragma unroll
    for (int s = 0; s < SPW; ++s) {
        const float a = alpha[s];
        y[s][0] = v[s][0].x;
        y[s][1] = fmaf(a, y[s][0], v[s][0].y);
        y[s][2] = fmaf(a, y[s][1], v[s][0].z);
        y[s][3] = fmaf(a, y[s][2], v[s][0].w);
        y[s][4] = fmaf(a, y[s][3], v[s][1].x);
        y[s][5] = fmaf(a, y[s][4], v[s][1].y);
        y[s][6] = fmaf(a, y[s][5], v[s][1].z);
        y[s][7] = fmaf(a, y[s][6], v[s][1].w);
    }

    // Segment transforms: s_out = A * s_in + Bc, A = alpha^8
    float A[SPW], Bc[SPW];
    #pragma unroll
    for (int s = 0; s < SPW; ++s) {
        const float a2 = alpha[s] * alpha[s];
        const float a4 = a2 * a2;
        A[s]  = a4 * a4;
        Bc[s] = y[s][7];
    }

    // Interleaved wave-inclusive scan of 4 independent transform streams
    #pragma unroll
    for (int off = 1; off < 64; off <<= 1) {
        float aP[SPW], bP[SPW];
        #pragma unroll
        for (int s = 0; s < SPW; ++s) {
            aP[s] = __shfl_up(A[s],  off);
            bP[s] = __shfl_up(Bc[s], off);
        }
        if (lane >= off) {
            #pragma unroll
            for (int s = 0; s < SPW; ++s) {
                Bc[s] = fmaf(A[s], bP[s], Bc[s]);
                A[s]  = A[s] * aP[s];
            }
        }
    }

    // Exclusive: incoming state = previous lane's inclusive B
    float s_in[SPW];
    #pragma unroll
    for (int s = 0; s < SPW; ++s) {
        float t = __shfl_up(Bc[s], 1);
        s_in[s] = (lane == 0) ? 0.0f : t;
    }

    // Fixup: y[j] += alpha^(j+1) * s_in
    #pragma unroll
    for (int s = 0; s < SPW; ++s) {
        float pw = alpha[s];
        #pragma unroll
        for (int j = 0; j < 8; ++j) {
            y[s][j] = fmaf(pw, s_in[s], y[s][j]);
            pw *= alpha[s];
        }
    }

    // Nontemporal float4 stores (don't cache the write stream)
    float* op = psp + (size_t)seq0 * TT + (size_t)lane * 8;
    #pragma unroll
    for (int s = 0; s < SPW; ++s) {
        f32x4 o0 = {y[s][0], y[s][1], y[s][2], y[s][3]};
        f32x4 o1 = {y[s][4], y[s][5], y[s][6], y[s][7]};
        __builtin_nontemporal_store(o0, reinterpret_cast<f32x4*>(op + (size_t)s * TT));
        __builtin_nontemporal_store(o1, reinterpret_cast<f32x4*>(op + (size_t)s * TT + 4));
    }

    if (lane == 63) {
        // final states for the 4 sequences are contiguous & 16B-aligned
        f32x4 fs = {y[0][7], y[1][7], y[2][7], y[3][7]};
        *reinterpret_cast<f32x4*>(final_state + seq0) = fs;
    }
}

extern "C" void kernel_launch(void* const* d_in, const int* in_sizes, int n_in,
                              void* d_out, int out_size, void* d_ws, size_t ws_size,
                              hipStream_t stream) {
    const float* x     = (const float*)d_in[0];   // [B, D, T]
    const float* alpha = (const float*)d_in[1];   // [D]
    float* psp         = (float*)d_out;                      // [B, D, T]
    float* final_state = (float*)d_out + (size_t)NSEQ * TT;  // [B, D]

    // NSEQ/SPW = 16384 waves, 4 waves per 256-thread block -> 4096 blocks
    const int blocks = NSEQ / (SPW * 4);
    ema_scan4_kernel<<<blocks, 256, 0, stream>>>(x, alpha, psp, final_state);
}

// Round 4
// 48.177 us; speedup vs baseline: 1.7529x; 1.7529x over previous
//
#include <hip/hip_runtime.h>

// EMA / first-order low-pass scan: s_t = alpha[d] * s_{t-1} + x[b,d,t]
// x: [B, D, T] fp32 contiguous; alpha: [D] fp32.
// out: psp [B,D,T] followed by final_state [B,D] (flat, fp32).
//
// One 64-lane wave processes SPW=4 consecutive sequences (same b, d0..d0+3):
//  - 8 independent float4 loads issued up front (4x MLP vs 1-seq version)
//  - 4 independent wave-scans interleaved for ILP in the shfl chain
//  - plain float4 stores (nontemporal 'nt' stores REGRESSED: WRITE_SIZE
//    131.6 -> 228.4 MB on gfx950; L2 write-coalescing defeated)

#define BB 32
#define DD 2048
#define TT 512
#define NSEQ (BB * DD)   // 65536 sequences
#define SPW 4            // sequences per wave

typedef float f32x4 __attribute__((ext_vector_type(4)));

__global__ __launch_bounds__(256) void ema_scan4_kernel(
    const float* __restrict__ x,
    const float* __restrict__ alpha_arr,
    float* __restrict__ psp,
    float* __restrict__ final_state)
{
    const int gtid = blockIdx.x * 256 + threadIdx.x;
    const int wave = gtid >> 6;
    const int lane = threadIdx.x & 63;
    const int seq0 = wave * SPW;
    if (seq0 >= NSEQ) return;

    // 4 consecutive seqs share b; d = d0..d0+3 (d0 % 4 == 0) -> one float4 alpha load
    const int d0 = seq0 & (DD - 1);
    const f32x4 al4 = *reinterpret_cast<const f32x4*>(alpha_arr + d0);
    const float alpha[SPW] = {al4.x, al4.y, al4.z, al4.w};

    const float* xp = x + (size_t)seq0 * TT + (size_t)lane * 8;

    // Issue all 8 loads back-to-back (independent -> 128 B/lane in flight)
    f32x4 v[SPW][2];
    #pragma unroll
    for (int s = 0; s < SPW; ++s) {
        v[s][0] = *reinterpret_cast<const f32x4*>(xp + (size_t)s * TT);
        v[s][1] = *reinterpret_cast<const f32x4*>(xp + (size_t)s * TT + 4);
    }

    // Local inclusive scans (4 independent 8-FMA chains -> ILP)
    float y[SPW][8];
    #pragma unroll
    for (int s = 0; s < SPW; ++s) {
        const float a = alpha[s];
        y[s][0] = v[s][0].x;
        y[s][1] = fmaf(a, y[s][0], v[s][0].y);
        y[s][2] = fmaf(a, y[s][1], v[s][0].z);
        y[s][3] = fmaf(a, y[s][2], v[s][0].w);
        y[s][4] = fmaf(a, y[s][3], v[s][1].x);
        y[s][5] = fmaf(a, y[s][4], v[s][1].y);
        y[s][6] = fmaf(a, y[s][5], v[s][1].z);
        y[s][7] = fmaf(a, y[s][6], v[s][1].w);
    }

    // Segment transforms: s_out = A * s_in + Bc, A = alpha^8
    float A[SPW], Bc[SPW];
    #pragma unroll
    for (int s = 0; s < SPW; ++s) {
        const float a2 = alpha[s] * alpha[s];
        const float a4 = a2 * a2;
        A[s]  = a4 * a4;
        Bc[s] = y[s][7];
    }

    // Interleaved wave-inclusive scan of 4 independent transform streams
    #pragma unroll
    for (int off = 1; off < 64; off <<= 1) {
        float aP[SPW], bP[SPW];
        #pragma unroll
        for (int s = 0; s < SPW; ++s) {
            aP[s] = __shfl_up(A[s],  off);
            bP[s] = __shfl_up(Bc[s], off);
        }
        if (lane >= off) {
            #pragma unroll
            for (int s = 0; s < SPW; ++s) {
                Bc[s] = fmaf(A[s], bP[s], Bc[s]);
                A[s]  = A[s] * aP[s];
            }
        }
    }

    // Exclusive: incoming state = previous lane's inclusive B
    float s_in[SPW];
    #pragma unroll
    for (int s = 0; s < SPW; ++s) {
        float t = __shfl_up(Bc[s], 1);
        s_in[s] = (lane == 0) ? 0.0f : t;
    }

    // Fixup: y[j] += alpha^(j+1) * s_in
    #pragma unroll
    for (int s = 0; s < SPW; ++s) {
        float pw = alpha[s];
        #pragma unroll
        for (int j = 0; j < 8; ++j) {
            y[s][j] = fmaf(pw, s_in[s], y[s][j]);
            pw *= alpha[s];
        }
    }

    // Plain coalesced float4 stores
    float* op = psp + (size_t)seq0 * TT + (size_t)lane * 8;
    #pragma unroll
    for (int s = 0; s < SPW; ++s) {
        f32x4 o0 = {y[s][0], y[s][1], y[s][2], y[s][3]};
        f32x4 o1 = {y[s][4], y[s][5], y[s][6], y[s][7]};
        *reinterpret_cast<f32x4*>(op + (size_t)s * TT)     = o0;
        *reinterpret_cast<f32x4*>(op + (size_t)s * TT + 4) = o1;
    }

    if (lane == 63) {
        // final states for the 4 sequences are contiguous & 16B-aligned
        f32x4 fs = {y[0][7], y[1][7], y[2][7], y[3][7]};
        *reinterpret_cast<f32x4*>(final_state + seq0) = fs;
    }
}

extern "C" void kernel_launch(void* const* d_in, const int* in_sizes, int n_in,
                              void* d_out, int out_size, void* d_ws, size_t ws_size,
                              hipStream_t stream) {
    const float* x     = (const float*)d_in[0];   // [B, D, T]
    const float* alpha = (const float*)d_in[1];   // [D]
    float* psp         = (float*)d_out;                      // [B, D, T]
    float* final_state = (float*)d_out + (size_t)NSEQ * TT;  // [B, D]

    // NSEQ/SPW = 16384 waves, 4 waves per 256-thread block -> 4096 blocks
    const int blocks = NSEQ / (SPW * 4);
    ema_scan4_kernel<<<blocks, 256, 0, stream>>>(x, alpha, psp, final_state);
}